// Round 8
// baseline (463.019 us; speedup 1.0000x reference)
//
#include <hip/hip_runtime.h>
#include <hip/hip_bf16.h>

// Problem constants
#define Bz   2
#define Lz   2048
#define CINz 20
#define DMz  128
#define DIz  256
#define DSz  16
#define DTRz 8
#define DCz  4
#define NLz  6
#define NCz  6
#define EPSz 1e-5f
#define CHUNK 8
#define NCH   256   // Lz / CHUNK
#define XT    8     // tokens per xprojc block

__device__ __forceinline__ float siluf(float x){ return x / (1.0f + expf(-x)); }
__device__ __forceinline__ float softplusf(float x){ return (x > 20.f) ? x : log1pf(expf(x)); }

// ---- K1: embed = rmsnorm(input_ids) @ in2m_w.T + b, silu -> hs (B,L,DM)
__global__ void k_embed(const float* __restrict__ ids, const float* __restrict__ nw,
                        const float* __restrict__ w, const float* __restrict__ b,
                        float* __restrict__ hs){
  int tok = blockIdx.x;          // B*L
  int t = threadIdx.x;           // DM=128
  __shared__ float xs[CINz];
  if (t < CINz) xs[t] = ids[tok*CINz + t];
  __syncthreads();
  float ss = 0.f;
  #pragma unroll
  for (int k=0;k<CINz;k++){ float v = xs[k]; ss += v*v; }
  float rs = rsqrtf(ss/(float)CINz + EPSz);
  float acc = b[t];
  const float* wr = w + (size_t)t*CINz;
  #pragma unroll
  for (int k=0;k<CINz;k++) acc += xs[k]*rs*nw[k]*wr[k];
  hs[tok*DMz + t] = siluf(acc);
}

// ---- K2: fused {res update + rmsnorm} + GEMM  xz = norm(hs0+hs1+res_old) @ in_w.T
//      M=4096 N=512 K=128; tile 32x64, grid (128,8). nb==0 block writes res_new.
__global__ void k_gemm_in(const float* __restrict__ hs0, const float* __restrict__ hs1,
                          const float* __restrict__ res_old, float* __restrict__ res_new,
                          const float* __restrict__ norm_w, const float* __restrict__ in_w,
                          float* __restrict__ xin, float* __restrict__ zb, int first){
  __shared__ __align__(16) float As[32][132];
  __shared__ __align__(16) float Ws[64][132];
  __shared__ float ssp[32][9];
  __shared__ float rsArr[32];
  int tb = blockIdx.x, nb = blockIdx.y, tid = threadIdx.x;
  int row = tid & 31, seg = tid >> 5;     // 32 rows x 8 segs of 16 cols
  size_t goff = (size_t)(tb*32+row)*DMz + seg*16;
  float4 r2[4];
  #pragma unroll
  for (int q=0;q<4;q++){
    float4 v = *(const float4*)(hs0 + goff + q*4);
    if (!first){
      float4 v1 = *(const float4*)(hs1 + goff + q*4);
      float4 vr = *(const float4*)(res_old + goff + q*4);
      v.x += v1.x+vr.x; v.y += v1.y+vr.y; v.z += v1.z+vr.z; v.w += v1.w+vr.w;
    }
    r2[q] = v;
  }
  float ss = 0.f;
  #pragma unroll
  for (int q=0;q<4;q++) ss += r2[q].x*r2[q].x + r2[q].y*r2[q].y + r2[q].z*r2[q].z + r2[q].w*r2[q].w;
  ssp[row][seg] = ss;
  __syncthreads();
  if (tid < 32){
    float s2 = 0.f;
    #pragma unroll
    for (int k=0;k<8;k++) s2 += ssp[tid][k];
    rsArr[tid] = rsqrtf(s2*(1.0f/DMz) + EPSz);
  }
  __syncthreads();
  float rs = rsArr[row];
  #pragma unroll
  for (int q=0;q<4;q++){
    float4 nw = *(const float4*)(norm_w + seg*16 + q*4);
    float4 o = make_float4(r2[q].x*rs*nw.x, r2[q].y*rs*nw.y, r2[q].z*rs*nw.z, r2[q].w*rs*nw.w);
    *(float4*)&As[row][seg*16 + q*4] = o;
    if (nb == 0) *(float4*)(res_new + goff + q*4) = r2[q];
  }
  // stage W: 64 rows x 128
  #pragma unroll
  for (int i=tid; i<64*DMz/4; i+=256){
    int r = i >> 5, c4 = i & 31;
    *(float4*)&Ws[r][c4*4] = *(const float4*)(in_w + (size_t)(nb*64+r)*DMz + c4*4);
  }
  __syncthreads();
  int tp = tid >> 4;      // token pair 0..15
  int cl = tid & 15;      // col lane; cols cl+16j
  float acc[2][4] = {};
  for (int k=0;k<DMz;k+=4){
    float4 a0 = *(const float4*)&As[tp*2+0][k];
    float4 a1 = *(const float4*)&As[tp*2+1][k];
    #pragma unroll
    for (int j=0;j<4;j++){
      float4 w = *(const float4*)&Ws[cl+16*j][k];
      acc[0][j] = fmaf(a0.x,w.x, fmaf(a0.y,w.y, fmaf(a0.z,w.z, fmaf(a0.w,w.w, acc[0][j]))));
      acc[1][j] = fmaf(a1.x,w.x, fmaf(a1.y,w.y, fmaf(a1.z,w.z, fmaf(a1.w,w.w, acc[1][j]))));
    }
  }
  #pragma unroll
  for (int i=0;i<2;i++){
    int gt = tb*32 + tp*2 + i;
    #pragma unroll
    for (int j=0;j<4;j++){
      int c = nb*64 + cl + 16*j;
      if (c < DIz) xin[(size_t)gt*DIz + c] = acc[i][j];
      else         zb [(size_t)gt*DIz + (c-DIz)] = acc[i][j];
    }
  }
}

// ---- K4: fused conv+silu + xproj + dt for an 8-token tile; xp_w staged in LDS
__global__ void k_xprojc(const float* __restrict__ xin, const float* __restrict__ cw,
                         const float* __restrict__ cb, const float* __restrict__ xp_w,
                         const float* __restrict__ dt_w, const float* __restrict__ dt_b,
                         float* __restrict__ dt, float* __restrict__ Bm, float* __restrict__ Cm){
  __shared__ __align__(16) float xs[XT+3][DIz];   // 11.3 KB
  __shared__ __align__(16) float us[XT][DIz];     // 8 KB
  __shared__ __align__(16) float Wl[40][264];     // 42.2 KB
  __shared__ float xd[XT][40];
  int tb = blockIdx.x;           // 0..511
  int b  = tb >> 8;
  int l0 = (tb & 255) * XT;
  int tid = threadIdx.x;
  // stage xin rows l0-3 .. l0+XT-1 (zero-pad l<0)
  for (int i = tid; i < (XT+3)*(DIz/4); i += 256){
    int r = i >> 6, c4 = (i & 63)*4;
    int l = l0 - 3 + r;
    float4 v = make_float4(0,0,0,0);
    if (l >= 0) v = *(const float4*)(xin + ((size_t)(b*Lz + l))*DIz + c4);
    *(float4*)&xs[r][c4] = v;
  }
  // stage xp_w: 40 rows x 256
  #pragma unroll
  for (int i = tid; i < 40*(DIz/4); i += 256){
    int r = i >> 6, c4 = (i & 63)*4;
    *(float4*)&Wl[r][c4] = *(const float4*)(xp_w + (size_t)r*DIz + c4);
  }
  __syncthreads();
  // conv+silu into us: thread d = tid
  {
    int d = tid;
    float c0 = cw[d*DCz+0], c1 = cw[d*DCz+1], c2 = cw[d*DCz+2], c3 = cw[d*DCz+3];
    float bb = cb[d];
    #pragma unroll
    for (int tt=0; tt<XT; tt++){
      float acc = bb + xs[tt][d]*c0 + xs[tt+1][d]*c1 + xs[tt+2][d]*c2 + xs[tt+3][d]*c3;
      us[tt][d] = acc / (1.f + __expf(-acc));
    }
  }
  __syncthreads();
  // xdbl: 160 threads: c = t>>2 (0..39), kg = t&3; dot over 64 k-elems each, W from LDS
  if (tid < 160){
    int c = tid >> 2, kg = tid & 3;
    #pragma unroll
    for (int tt=0; tt<XT; tt++){
      float a = 0.f;
      #pragma unroll
      for (int m=0;m<16;m++){
        float4 uv = *(const float4*)&us[tt][kg*4 + m*16];
        float4 wv = *(const float4*)&Wl[c][kg*4 + m*16];
        a += uv.x*wv.x + uv.y*wv.y + uv.z*wv.z + uv.w*wv.w;
      }
      a += __shfl_down(a, 2);
      a += __shfl_down(a, 1);
      if (kg == 0) xd[tt][c] = a;
    }
  }
  __syncthreads();
  // dt: thread d for all XT tokens; Bm/Cm split writes
  {
    int d = tid;
    float w0[DTRz];
    #pragma unroll
    for (int k=0;k<DTRz;k++) w0[k] = dt_w[(size_t)d*DTRz + k];
    float bias = dt_b[d];
    #pragma unroll
    for (int tt=0; tt<XT; tt++){
      float s = bias;
      #pragma unroll
      for (int k=0;k<DTRz;k++) s += xd[tt][k]*w0[k];
      dt[((size_t)(b*Lz + l0 + tt))*DIz + d] = softplusf(s);
    }
    if (tid < XT*DSz){
      int tt = tid >> 4, s2 = tid & 15;
      Bm[((size_t)(b*Lz + l0 + tt))*DSz + s2] = xd[tt][DTRz + s2];
      Cm[((size_t)(b*Lz + l0 + tt))*DSz + s2] = xd[tt][DTRz + DSz + s2];
    }
  }
}

// ---- K5: chunk-local scan, thread-per-d, 16 states in regs; conv inline; store H + sum(dt)
__global__ void k_scan1(const float* __restrict__ xin, const float* __restrict__ dt,
                        const float* __restrict__ Bm,
                        const float* __restrict__ cw, const float* __restrict__ cb,
                        const float* __restrict__ A_log,
                        float* __restrict__ Sdt, float* __restrict__ H){
  int bid = blockIdx.x;           // Bz*NCH = 512
  int b = bid >> 8;
  int ch = bid & (NCH-1);
  int d = threadIdx.x;
  __shared__ float B_l[CHUNK][DSz];
  if (threadIdx.x < CHUNK*DSz){
    int tt = threadIdx.x >> 4, s = threadIdx.x & 15;
    B_l[tt][s] = Bm[((size_t)(b*Lz + ch*CHUNK + tt))*DSz + s];
  }
  float Av[DSz];
  #pragma unroll
  for (int q=0;q<4;q++){
    float4 al = *(const float4*)(A_log + d*DSz + q*4);
    Av[q*4+0] = -__expf(al.x); Av[q*4+1] = -__expf(al.y);
    Av[q*4+2] = -__expf(al.z); Av[q*4+3] = -__expf(al.w);
  }
  float c0=cw[d*DCz],c1=cw[d*DCz+1],c2=cw[d*DCz+2],c3=cw[d*DCz+3], bb=cb[d];
  int l0 = ch*CHUNK;
  size_t base = (size_t)(b*Lz + l0)*DIz + d;
  float w0=0.f, w1=0.f, w2=0.f;
  if (l0 >= 3){ w0 = xin[base - 3*DIz]; w1 = xin[base - 2*DIz]; w2 = xin[base - DIz]; }
  __syncthreads();
  float h[DSz];
  float sdt = 0.f;
  #pragma unroll
  for (int s=0;s<DSz;s++) h[s]=0.f;
  #pragma unroll
  for (int tt=0; tt<CHUNK; tt++){
    float w3  = xin[base + (size_t)tt*DIz];
    float dtv = dt[base + (size_t)tt*DIz];
    float uacc = bb + w0*c0 + w1*c1 + w2*c2 + w3*c3;
    float u = uacc / (1.f + __expf(-uacc));
    w0=w1; w1=w2; w2=w3;
    float x = dtv*u;
    sdt += dtv;
    #pragma unroll
    for (int s=0;s<DSz;s++){
      float a = __expf(dtv*Av[s]);
      h[s] = a*h[s] + x*B_l[tt][s];
    }
  }
  Sdt[(size_t)(ch*Bz + b)*DIz + d] = sdt;
  size_t o = ((size_t)(ch*Bz + b)*DIz + d)*DSz;
  #pragma unroll
  for (int q=0;q<4;q++)
    *(float4*)(H + o + q*4) = make_float4(h[q*4],h[q*4+1],h[q*4+2],h[q*4+3]);
}

// ---- K6: sequential combine across NCH chunks; P recomputed as exp(Av * sum_dt)
__global__ void k_scan2(const float* __restrict__ Sdt, const float* __restrict__ H,
                        const float* __restrict__ A_log, float* __restrict__ hstart){
  int idx = blockIdx.x*256 + threadIdx.x;   // B*DI*DS = 8192
  int ds = (idx >> 4) & 255;                // d
  int s  = idx & 15;
  int bd = idx >> 4;                        // b*DIz + d
  float Av = -__expf(A_log[ds*DSz + s]);
  float h = 0.f;
  for (int c0=0; c0<NCH; c0+=32){
    float sd[32], q[32];
    #pragma unroll
    for (int j=0;j<32;j++){
      sd[j] = Sdt[(size_t)(c0+j)*(Bz*DIz) + bd];
      q[j]  = H[(size_t)(c0+j)*(Bz*DIz*DSz) + idx];
    }
    #pragma unroll
    for (int j=0;j<32;j++){
      size_t o = (size_t)(c0+j)*(Bz*DIz*DSz) + idx;
      hstart[o] = h;
      h = __expf(sd[j]*Av)*h + q[j];
    }
  }
}

// ---- K7: replay chunk with correct h0, produce y, gate -> yg
__global__ void k_scan3(const float* __restrict__ xin, const float* __restrict__ dt,
                        const float* __restrict__ Bm, const float* __restrict__ Cm,
                        const float* __restrict__ z,
                        const float* __restrict__ cw, const float* __restrict__ cb,
                        const float* __restrict__ A_log, const float* __restrict__ Dp,
                        const float* __restrict__ hstart, float* __restrict__ yg){
  int bid = blockIdx.x;
  int b = bid >> 8;
  int ch = bid & (NCH-1);
  int d = threadIdx.x;
  __shared__ float B_l[CHUNK][DSz], C_l[CHUNK][DSz];
  if (threadIdx.x < CHUNK*DSz){
    int tt = threadIdx.x >> 4, s = threadIdx.x & 15;
    B_l[tt][s] = Bm[((size_t)(b*Lz + ch*CHUNK + tt))*DSz + s];
  } else if (threadIdx.x < 2*CHUNK*DSz){
    int t2 = threadIdx.x - CHUNK*DSz;
    int tt = t2 >> 4, s = t2 & 15;
    C_l[tt][s] = Cm[((size_t)(b*Lz + ch*CHUNK + tt))*DSz + s];
  }
  float Av[DSz];
  #pragma unroll
  for (int q=0;q<4;q++){
    float4 al = *(const float4*)(A_log + d*DSz + q*4);
    Av[q*4+0] = -__expf(al.x); Av[q*4+1] = -__expf(al.y);
    Av[q*4+2] = -__expf(al.z); Av[q*4+3] = -__expf(al.w);
  }
  float c0=cw[d*DCz],c1=cw[d*DCz+1],c2=cw[d*DCz+2],c3=cw[d*DCz+3], bb=cb[d];
  float Dv = Dp[d];
  int l0 = ch*CHUNK;
  size_t base = (size_t)(b*Lz + l0)*DIz + d;
  float w0=0.f, w1=0.f, w2=0.f;
  if (l0 >= 3){ w0 = xin[base - 3*DIz]; w1 = xin[base - 2*DIz]; w2 = xin[base - DIz]; }
  float h[DSz];
  {
    size_t o = ((size_t)(ch*Bz + b)*DIz + d)*DSz;
    #pragma unroll
    for (int q=0;q<4;q++){
      float4 hv = *(const float4*)(hstart + o + q*4);
      h[q*4+0]=hv.x; h[q*4+1]=hv.y; h[q*4+2]=hv.z; h[q*4+3]=hv.w;
    }
  }
  __syncthreads();
  #pragma unroll
  for (int tt=0; tt<CHUNK; tt++){
    float w3  = xin[base + (size_t)tt*DIz];
    float dtv = dt[base + (size_t)tt*DIz];
    float zv  = z[base + (size_t)tt*DIz];
    float uacc = bb + w0*c0 + w1*c1 + w2*c2 + w3*c3;
    float u = uacc / (1.f + __expf(-uacc));
    w0=w1; w1=w2; w2=w3;
    float x = dtv*u;
    float y = 0.f;
    #pragma unroll
    for (int s=0;s<DSz;s++){
      float a = __expf(dtv*Av[s]);
      h[s] = a*h[s] + x*B_l[tt][s];
      y += h[s]*C_l[tt][s];
    }
    float yv = y + u*Dv;
    yg[base + (size_t)tt*DIz] = yv * (zv / (1.f + __expf(-zv)));
  }
}

// ---- K8: hs_part[kz] = yg @ out_w.T  M=4096 N=128 K=256; grid (128,2,2)
__global__ void k_gemm_out(const float* __restrict__ yg, const float* __restrict__ out_w,
                           float* __restrict__ hs0, float* __restrict__ hs1){
  __shared__ __align__(16) float As[32][132];
  __shared__ __align__(16) float Ws[64][132];
  int tb = blockIdx.x, nb = blockIdx.y, kz = blockIdx.z, tid = threadIdx.x;
  int k0 = kz*128;
  #pragma unroll
  for (int i=tid; i<32*128/4; i+=256){
    int row = i >> 5, c4 = i & 31;
    *(float4*)&As[row][c4*4] = *(const float4*)(yg + (size_t)(tb*32+row)*DIz + k0 + c4*4);
  }
  #pragma unroll
  for (int i=tid; i<64*128/4; i+=256){
    int row = i >> 5, c4 = i & 31;
    *(float4*)&Ws[row][c4*4] = *(const float4*)(out_w + (size_t)(nb*64+row)*DIz + k0 + c4*4);
  }
  __syncthreads();
  int tp = tid >> 4;
  int cl = tid & 15;
  float acc[2][4] = {};
  for (int k=0;k<128;k+=4){
    float4 a0 = *(const float4*)&As[tp*2+0][k];
    float4 a1 = *(const float4*)&As[tp*2+1][k];
    #pragma unroll
    for (int j=0;j<4;j++){
      float4 w = *(const float4*)&Ws[cl+16*j][k];
      acc[0][j] = fmaf(a0.x,w.x, fmaf(a0.y,w.y, fmaf(a0.z,w.z, fmaf(a0.w,w.w, acc[0][j]))));
      acc[1][j] = fmaf(a1.x,w.x, fmaf(a1.y,w.y, fmaf(a1.z,w.z, fmaf(a1.w,w.w, acc[1][j]))));
    }
  }
  float* dst = kz ? hs1 : hs0;
  #pragma unroll
  for (int i=0;i<2;i++){
    int gt = tb*32 + tp*2 + i;
    #pragma unroll
    for (int j=0;j<4;j++){
      dst[(size_t)gt*DMz + nb*64 + cl + 16*j] = acc[i][j];
    }
  }
}

// ---- K9: final rmsnorm(hs0+hs1+res) @ head_w.T + head_b, softmax -> out
__global__ void k_head(const float* __restrict__ hs0, const float* __restrict__ hs1,
                       const float* __restrict__ res,
                       const float* __restrict__ nfw, const float* __restrict__ hw,
                       const float* __restrict__ hb, float* __restrict__ out){
  int b = blockIdx.x; int t = threadIdx.x;   // 128
  __shared__ float xs[DMz];
  __shared__ float logits[NCz];
  int tok = b*Lz + (Lz-1);
  xs[t] = hs0[tok*DMz + t] + hs1[tok*DMz + t] + res[tok*DMz + t];
  __syncthreads();
  float ss = 0.f;
  #pragma unroll
  for (int k=0;k<DMz;k++){ float v = xs[k]; ss += v*v; }
  float rs = rsqrtf(ss/(float)DMz + EPSz);
  if (t < NCz){
    float a = hb[t];
    const float* wr = hw + (size_t)t*DMz;
    for (int k=0;k<DMz;k++) a += xs[k]*rs*nfw[k]*wr[k];
    logits[t] = a;
  }
  __syncthreads();
  if (t == 0){
    float m = logits[0];
    for (int c=1;c<NCz;c++) m = fmaxf(m, logits[c]);
    float ssum = 0.f; float e[NCz];
    for (int c=0;c<NCz;c++){ e[c] = expf(logits[c]-m); ssum += e[c]; }
    for (int c=0;c<NCz;c++) out[b*NCz + c] = e[c]/ssum;
  }
}

extern "C" void kernel_launch(void* const* d_in, const int* in_sizes, int n_in,
                              void* d_out, int out_size, void* d_ws, size_t ws_size,
                              hipStream_t stream){
  const float* input_ids  = (const float*)d_in[0];
  const float* in_norm_w  = (const float*)d_in[1];
  const float* in2m_w     = (const float*)d_in[2];
  const float* in2m_b     = (const float*)d_in[3];
  const float* norm_w     = (const float*)d_in[4];
  const float* in_proj_w  = (const float*)d_in[5];
  const float* conv_w     = (const float*)d_in[6];
  const float* conv_b     = (const float*)d_in[7];
  const float* x_proj_w   = (const float*)d_in[8];
  const float* dt_proj_w  = (const float*)d_in[9];
  const float* dt_proj_b  = (const float*)d_in[10];
  const float* A_log      = (const float*)d_in[11];
  const float* D_param    = (const float*)d_in[12];
  const float* out_proj_w = (const float*)d_in[13];
  const float* norm_f_w   = (const float*)d_in[14];
  const float* head_w     = (const float*)d_in[15];
  const float* head_b     = (const float*)d_in[16];

  float* ws   = (float*)d_ws;
  float* res0 = ws;                  // B*L*DM = 524288
  float* res1 = res0 + 524288;
  float* hs0  = res1 + 524288;       // B*L*DM
  float* hs1  = hs0  + 524288;
  float* xin  = hs1  + 524288;       // B*L*DI
  float* zb   = xin  + 1048576;
  float* yg   = zb   + 1048576;
  float* dtb  = yg   + 1048576;
  float* Bmb  = dtb  + 1048576;      // B*L*DS = 65536
  float* Cmb  = Bmb  + 65536;
  float* Sdt  = Cmb  + 65536;        // NCH*B*DI = 131072
  float* Hb   = Sdt  + 131072;       // NCH*B*DI*DS = 2097152
  float* hst  = Hb   + 2097152;

  k_embed<<<Bz*Lz, DMz, 0, stream>>>(input_ids, in_norm_w, in2m_w, in2m_b, hs0);
  for (int i=0;i<NLz;i++){
    float* resR = (i & 1) ? res1 : res0;     // read (layer i-1's write)
    float* resW = (i & 1) ? res0 : res1;     // write
    // note: i=0 writes res1 (resW when i&1==0 is res1)
    resW = (i & 1) ? res0 : res1;
    resR = (i & 1) ? res1 : res0;
    k_gemm_in<<<dim3(128, 8), 256, 0, stream>>>(hs0, hs1, resR, resW, norm_w + i*DMz,
                                                in_proj_w + (size_t)i*2*DIz*DMz, xin, zb, i==0);
    k_xprojc<<<(Bz*Lz)/XT, 256, 0, stream>>>(xin, conv_w + i*DIz*DCz, conv_b + i*DIz,
                                             x_proj_w + (size_t)i*(DTRz+2*DSz)*DIz,
                                             dt_proj_w + (size_t)i*DIz*DTRz, dt_proj_b + i*DIz,
                                             dtb, Bmb, Cmb);
    k_scan1<<<Bz*NCH, 256, 0, stream>>>(xin, dtb, Bmb, conv_w + i*DIz*DCz, conv_b + i*DIz,
                                        A_log + i*DIz*DSz, Sdt, Hb);
    k_scan2<<<(Bz*DIz*DSz)/256, 256, 0, stream>>>(Sdt, Hb, A_log + i*DIz*DSz, hst);
    k_scan3<<<Bz*NCH, 256, 0, stream>>>(xin, dtb, Bmb, Cmb, zb,
                                        conv_w + i*DIz*DCz, conv_b + i*DIz,
                                        A_log + i*DIz*DSz, D_param + i*DIz, hst, yg);
    k_gemm_out<<<dim3(128, 2, 2), 256, 0, stream>>>(yg, out_proj_w + (size_t)i*DMz*DIz, hs0, hs1);
  }
  // final res = write of layer 5 = res1 (i=5: resW = res1)
  k_head<<<Bz, DMz, 0, stream>>>(hs0, hs1, res1, norm_f_w, head_w, head_b, (float*)d_out);
}